// Round 2
// baseline (120.871 us; speedup 1.0000x reference)
//
#include <hip/hip_runtime.h>

#define N_BATCH 128
#define IN_F 1024
#define OUT_F 1024
#define BT 4            // batch rows per block
#define JT 256          // output columns per block (= blockDim.x)

// out[b,j] = sum_i in[b,i]*W[i,j] + v[b,0]*B[0,j] + v[b,1]*B[1,j]
//          + bias[j] + c00[b]*bc[0,j] + c11[b]*bc[1,j]
// where u[b,r] = sum_i in[b,i]*A[i,r], v[b,p] = sum_r u[b,r]*codes[b,r,p]
__global__ __launch_bounds__(256) void geps_fused(
    const float* __restrict__ input,    // [128,1024]
    const float* __restrict__ codes,    // [128,2,2]
    const float* __restrict__ weight,   // [1024,1024] (i major, j minor)
    const float* __restrict__ A,        // [1024,2]
    const float* __restrict__ Bm,       // [2,1024]
    const float* __restrict__ bias,     // [1024]
    const float* __restrict__ bctx,     // [2,1024]
    float* __restrict__ out)            // [128,1024]
{
    __shared__ float s_in[BT][IN_F];    // 16 KB
    __shared__ float s_u[BT][2];
    __shared__ float s_vc[BT][4];       // v0, v1, c00, c11

    const int t = threadIdx.x;
    const int jBase = blockIdx.x * JT;
    const int bBase = blockIdx.y * BT;

    // ---- stage BT input rows into LDS (float4, coalesced) ----
    {
        const float4* gin = (const float4*)(input + (size_t)bBase * IN_F);
        float4* s4 = (float4*)(&s_in[0][0]);
        #pragma unroll
        for (int k = 0; k < (BT * IN_F / 4) / 256; ++k)
            s4[t + 256 * k] = gin[t + 256 * k];
    }
    __syncthreads();

    // ---- u[row][r] = dot(s_in[row], A[:,r]) : 8 groups of 32 lanes ----
    {
        const int g = t >> 5;            // 0..7
        const int lane = t & 31;
        const int row = g >> 1, r = g & 1;
        float p = 0.f;
        #pragma unroll 4
        for (int ii = 0; ii < IN_F / 32; ++ii) {
            const int i = lane + 32 * ii;
            p += s_in[row][i] * A[i * 2 + r];
        }
        #pragma unroll
        for (int off = 16; off > 0; off >>= 1)
            p += __shfl_down(p, off, 32);
        if (lane == 0) s_u[row][r] = p;
    }
    __syncthreads();

    if (t < BT) {
        const int b = bBase + t;
        const float u0 = s_u[t][0], u1 = s_u[t][1];
        const float c00 = codes[b * 4 + 0], c01 = codes[b * 4 + 1];
        const float c10 = codes[b * 4 + 2], c11 = codes[b * 4 + 3];
        s_vc[t][0] = u0 * c00 + u1 * c10;   // v[b,0]
        s_vc[t][1] = u0 * c01 + u1 * c11;   // v[b,1]
        s_vc[t][2] = c00;
        s_vc[t][3] = c11;
    }
    __syncthreads();

    // ---- main GEMM: thread owns column j, BT row-accumulators ----
    const int j = jBase + t;
    const float* wp = weight + j;
    float acc0 = 0.f, acc1 = 0.f, acc2 = 0.f, acc3 = 0.f;
    #pragma unroll 8
    for (int i = 0; i < IN_F; ++i) {
        const float w = wp[(size_t)i * OUT_F];   // coalesced across lanes
        acc0 += s_in[0][i] * w;                  // LDS broadcast (free)
        acc1 += s_in[1][i] * w;
        acc2 += s_in[2][i] * w;
        acc3 += s_in[3][i] * w;
    }

    // ---- epilogue: rank-2 correction + biases ----
    const float B0 = Bm[j], B1 = Bm[OUT_F + j];
    const float bi = bias[j];
    const float bc0 = bctx[j], bc1 = bctx[OUT_F + j];

    float accs[BT] = {acc0, acc1, acc2, acc3};
    #pragma unroll
    for (int row = 0; row < BT; ++row) {
        const float r = accs[row]
                      + s_vc[row][0] * B0 + s_vc[row][1] * B1
                      + bi
                      + s_vc[row][2] * bc0 + s_vc[row][3] * bc1;
        out[(size_t)(bBase + row) * OUT_F + j] = r;
    }
}

extern "C" void kernel_launch(void* const* d_in, const int* in_sizes, int n_in,
                              void* d_out, int out_size, void* d_ws, size_t ws_size,
                              hipStream_t stream) {
    const float* input = (const float*)d_in[0];
    const float* codes = (const float*)d_in[1];
    const float* weight = (const float*)d_in[2];
    const float* A = (const float*)d_in[3];
    const float* Bm = (const float*)d_in[4];
    const float* bias = (const float*)d_in[5];
    const float* bctx = (const float*)d_in[6];
    float* out = (float*)d_out;

    dim3 grid(OUT_F / JT, N_BATCH / BT);   // (4, 32) = 128 blocks
    dim3 block(256);
    geps_fused<<<grid, block, 0, stream>>>(input, codes, weight, A, Bm, bias, bctx, out);
}

// Round 3
// 85.391 us; speedup vs baseline: 1.4155x; 1.4155x over previous
//
#include <hip/hip_runtime.h>

#define N_BATCH 128
#define IN_F 1024
#define OUT_F 1024
#define J4 (OUT_F / 4)   // 256 float4 columns, one per thread

// ---------------- Kernel 1: split-K GEMM partials ----------------
// grid (N_BATCH/2, KC); block 256.
// Thread t owns columns 4t..4t+3; block handles rows bBase, bBase+1 and
// i-range [kIdx*CHUNK, (kIdx+1)*CHUNK). Partials -> ws[k][b][j].
template <int CHUNK>
__global__ __launch_bounds__(256) void gemm_partial(
    const float* __restrict__ input,    // [128,1024]
    const float* __restrict__ weight,   // [1024,1024]
    float* __restrict__ ws)             // [KC,128,1024] partials
{
    __shared__ float s_in[2][CHUNK];
    const int t = threadIdx.x;
    const int bBase = blockIdx.x * 2;
    const int kIdx = blockIdx.y;
    const int i0 = kIdx * CHUNK;

    // stage 2 rows x CHUNK of input (float4, coalesced)
    {
        const int n4 = CHUNK / 4;
        #pragma unroll
        for (int r = 0; r < 2; ++r) {
            const float4* src = (const float4*)(input + (size_t)(bBase + r) * IN_F + i0);
            float4* dst = (float4*)&s_in[r][0];
            for (int x = t; x < n4; x += 256) dst[x] = src[x];
        }
    }
    __syncthreads();

    const float4* wp = (const float4*)weight + (size_t)i0 * J4 + t;
    float4 acc0 = {0.f, 0.f, 0.f, 0.f};
    float4 acc1 = {0.f, 0.f, 0.f, 0.f};

    #pragma unroll 8
    for (int ii = 0; ii < CHUNK; ++ii) {
        const float4 w = wp[(size_t)ii * J4];   // 16B coalesced, L2-resident
        const float a0 = s_in[0][ii];           // LDS broadcast
        const float a1 = s_in[1][ii];
        acc0.x = fmaf(a0, w.x, acc0.x);
        acc0.y = fmaf(a0, w.y, acc0.y);
        acc0.z = fmaf(a0, w.z, acc0.z);
        acc0.w = fmaf(a0, w.w, acc0.w);
        acc1.x = fmaf(a1, w.x, acc1.x);
        acc1.y = fmaf(a1, w.y, acc1.y);
        acc1.z = fmaf(a1, w.z, acc1.z);
        acc1.w = fmaf(a1, w.w, acc1.w);
    }

    float4* wsp = (float4*)ws;
    const size_t base = ((size_t)kIdx * N_BATCH + bBase) * J4 + t;
    wsp[base] = acc0;
    wsp[base + J4] = acc1;
}

// ---------------- Kernel 2: reduce + rank-2 epilogue ----------------
// grid 128 (one block per batch row b); block 256 (thread t -> cols 4t..4t+3)
__global__ __launch_bounds__(256) void reduce_epilogue(
    const float* __restrict__ input,
    const float* __restrict__ codes,    // [128,2,2]
    const float* __restrict__ A,        // [1024,2]
    const float* __restrict__ Bm,       // [2,1024]
    const float* __restrict__ bias,     // [1024]
    const float* __restrict__ bctx,     // [2,1024]
    const float* __restrict__ ws,
    float* __restrict__ out,
    int kc)
{
    const int b = blockIdx.x;
    const int t = threadIdx.x;

    // ---- u[r] = dot(input[b], A[:,r]) via block reduction ----
    float p0 = 0.f, p1 = 0.f;
    for (int i = t; i < IN_F; i += 256) {
        const float x = input[(size_t)b * IN_F + i];
        p0 = fmaf(x, A[i * 2 + 0], p0);
        p1 = fmaf(x, A[i * 2 + 1], p1);
    }
    #pragma unroll
    for (int off = 32; off > 0; off >>= 1) {
        p0 += __shfl_down(p0, off, 64);
        p1 += __shfl_down(p1, off, 64);
    }
    __shared__ float s_part[4][2];
    __shared__ float s_v[4];            // v0, v1, c00, c11
    const int wave = t >> 6;
    if ((t & 63) == 0) { s_part[wave][0] = p0; s_part[wave][1] = p1; }
    __syncthreads();
    if (t == 0) {
        const float u0 = s_part[0][0] + s_part[1][0] + s_part[2][0] + s_part[3][0];
        const float u1 = s_part[0][1] + s_part[1][1] + s_part[2][1] + s_part[3][1];
        const float c00 = codes[b * 4 + 0], c01 = codes[b * 4 + 1];
        const float c10 = codes[b * 4 + 2], c11 = codes[b * 4 + 3];
        s_v[0] = fmaf(u0, c00, u1 * c10);   // v[b,0]
        s_v[1] = fmaf(u0, c01, u1 * c11);   // v[b,1]
        s_v[2] = c00;
        s_v[3] = c11;
    }
    __syncthreads();
    const float v0 = s_v[0], v1 = s_v[1], c00 = s_v[2], c11 = s_v[3];

    // ---- sum partials + epilogue ----
    const float4* wsp = (const float4*)ws;
    float4 sum = {0.f, 0.f, 0.f, 0.f};
    for (int k = 0; k < kc; ++k) {
        const float4 p = wsp[((size_t)k * N_BATCH + b) * J4 + t];
        sum.x += p.x; sum.y += p.y; sum.z += p.z; sum.w += p.w;
    }
    const float4 B0 = ((const float4*)Bm)[t];
    const float4 B1 = ((const float4*)Bm)[J4 + t];
    const float4 bi = ((const float4*)bias)[t];
    const float4 bc0 = ((const float4*)bctx)[t];
    const float4 bc1 = ((const float4*)bctx)[J4 + t];

    float4 r;
    r.x = sum.x + v0 * B0.x + v1 * B1.x + bi.x + c00 * bc0.x + c11 * bc1.x;
    r.y = sum.y + v0 * B0.y + v1 * B1.y + bi.y + c00 * bc0.y + c11 * bc1.y;
    r.z = sum.z + v0 * B0.z + v1 * B1.z + bi.z + c00 * bc0.z + c11 * bc1.z;
    r.w = sum.w + v0 * B0.w + v1 * B1.w + bi.w + c00 * bc0.w + c11 * bc1.w;
    ((float4*)out)[(size_t)b * J4 + t] = r;
}

extern "C" void kernel_launch(void* const* d_in, const int* in_sizes, int n_in,
                              void* d_out, int out_size, void* d_ws, size_t ws_size,
                              hipStream_t stream) {
    const float* input = (const float*)d_in[0];
    const float* codes = (const float*)d_in[1];
    const float* weight = (const float*)d_in[2];
    const float* A = (const float*)d_in[3];
    const float* Bm = (const float*)d_in[4];
    const float* bias = (const float*)d_in[5];
    const float* bctx = (const float*)d_in[6];
    float* out = (float*)d_out;
    float* ws = (float*)d_ws;

    // pick split-K factor by available workspace (constant across calls)
    const size_t per_chunk = (size_t)N_BATCH * OUT_F * sizeof(float); // 512 KB
    int kc;
    if (ws_size >= 8 * per_chunk)      kc = 8;
    else if (ws_size >= 4 * per_chunk) kc = 4;
    else if (ws_size >= 2 * per_chunk) kc = 2;
    else                               kc = 1;

    dim3 block(256);
    dim3 grid1(N_BATCH / 2, kc);
    switch (kc) {
        case 8: gemm_partial<128><<<grid1, block, 0, stream>>>(input, weight, ws); break;
        case 4: gemm_partial<256><<<grid1, block, 0, stream>>>(input, weight, ws); break;
        case 2: gemm_partial<512><<<grid1, block, 0, stream>>>(input, weight, ws); break;
        default: gemm_partial<1024><<<grid1, block, 0, stream>>>(input, weight, ws); break;
    }
    reduce_epilogue<<<dim3(N_BATCH), block, 0, stream>>>(
        input, codes, A, Bm, bias, bctx, ws, out, kc);
}

// Round 4
// 83.356 us; speedup vs baseline: 1.4501x; 1.0244x over previous
//
#include <hip/hip_runtime.h>

#define N_BATCH 128
#define IN_F 1024
#define OUT_F 1024
#define KC 16                 // split-K factor
#define CHUNK (IN_F / KC)     // 64
#define BT 16                 // batch rows per block (16 accumulators/thread)

// ---------------- Kernel 1: split-K GEMM partials ----------------
// grid (4 j-tiles, 8 b-tiles, KC); block 256.
// Thread t owns column j = jBase + t and BT rows; K-range [k*CHUNK,(k+1)*CHUNK).
// FLOP:L2-byte = 16*2/4 = 8 -> compute-bound (L2 weight traffic 32 MB total).
__global__ __launch_bounds__(256) void gemm_partial(
    const float* __restrict__ input,    // [128,1024]
    const float* __restrict__ weight,   // [1024,1024]
    float* __restrict__ ws)             // [KC,128,1024] partials
{
    __shared__ float s_in[BT][CHUNK];   // 4 KB
    const int t = threadIdx.x;
    const int jBase = blockIdx.x * 256;
    const int b0 = blockIdx.y * BT;
    const int k = blockIdx.z;
    const int i0 = k * CHUNK;

    // stage BT x CHUNK input slab (256 float4 = 1024 floats)
    {
        const int row = t >> 4;          // t / (CHUNK/4)
        const int x = t & 15;            // t % (CHUNK/4)
        ((float4*)&s_in[row][0])[x] =
            ((const float4*)(input + (size_t)(b0 + row) * IN_F + i0))[x];
    }
    __syncthreads();

    const int j = jBase + t;
    const float* wp = weight + (size_t)i0 * OUT_F + j;
    float acc[BT];
    #pragma unroll
    for (int r = 0; r < BT; ++r) acc[r] = 0.f;

    #pragma unroll 4
    for (int ii = 0; ii < CHUNK; ++ii) {
        const float w = wp[(size_t)ii * OUT_F];   // 4B coalesced across lanes
        #pragma unroll
        for (int r = 0; r < BT; ++r)
            acc[r] = fmaf(s_in[r][ii], w, acc[r]); // LDS broadcast (free)
    }

    float* o = ws + ((size_t)k * N_BATCH + b0) * OUT_F + j;
    #pragma unroll
    for (int r = 0; r < BT; ++r)
        o[(size_t)r * OUT_F] = acc[r];
}

// ---------------- Kernel 2: reduce + rank-2 epilogue ----------------
// grid (4 j-tiles, 128 b); block 256. Thread owns one output element.
__global__ __launch_bounds__(256) void reduce_epilogue(
    const float* __restrict__ input,
    const float* __restrict__ codes,    // [128,2,2]
    const float* __restrict__ A,        // [1024,2]
    const float* __restrict__ Bm,       // [2,1024]
    const float* __restrict__ bias,     // [1024]
    const float* __restrict__ bctx,     // [2,1024]
    const float* __restrict__ ws,
    float* __restrict__ out)
{
    const int t = threadIdx.x;
    const int b = blockIdx.y;
    const int j = blockIdx.x * 256 + t;

    // ---- u[r] = dot(input[b], A[:,r]) via block reduction ----
    float p0 = 0.f, p1 = 0.f;
    #pragma unroll
    for (int ii = 0; ii < IN_F / 256; ++ii) {
        const int i = t + 256 * ii;
        const float x = input[(size_t)b * IN_F + i];
        p0 = fmaf(x, A[i * 2 + 0], p0);
        p1 = fmaf(x, A[i * 2 + 1], p1);
    }
    #pragma unroll
    for (int off = 32; off > 0; off >>= 1) {
        p0 += __shfl_down(p0, off);
        p1 += __shfl_down(p1, off);
    }
    __shared__ float s_part[4][2];
    __shared__ float s_v[4];            // v0, v1, c00, c11
    const int wave = t >> 6;
    if ((t & 63) == 0) { s_part[wave][0] = p0; s_part[wave][1] = p1; }
    __syncthreads();
    if (t == 0) {
        const float u0 = s_part[0][0] + s_part[1][0] + s_part[2][0] + s_part[3][0];
        const float u1 = s_part[0][1] + s_part[1][1] + s_part[2][1] + s_part[3][1];
        const float c00 = codes[b * 4 + 0], c01 = codes[b * 4 + 1];
        const float c10 = codes[b * 4 + 2], c11 = codes[b * 4 + 3];
        s_v[0] = fmaf(u0, c00, u1 * c10);   // v[b,0]
        s_v[1] = fmaf(u0, c01, u1 * c11);   // v[b,1]
        s_v[2] = c00;
        s_v[3] = c11;
    }
    __syncthreads();
    const float v0 = s_v[0], v1 = s_v[1], c00 = s_v[2], c11 = s_v[3];

    // ---- sum KC partials (independent loads, all in flight) ----
    float sum = 0.f;
    #pragma unroll
    for (int k = 0; k < KC; ++k)
        sum += ws[((size_t)k * N_BATCH + b) * OUT_F + j];

    const float r = sum
                  + v0 * Bm[j] + v1 * Bm[OUT_F + j]
                  + bias[j]
                  + c00 * bctx[j] + c11 * bctx[OUT_F + j];
    out[(size_t)b * OUT_F + j] = r;
}

extern "C" void kernel_launch(void* const* d_in, const int* in_sizes, int n_in,
                              void* d_out, int out_size, void* d_ws, size_t ws_size,
                              hipStream_t stream) {
    const float* input = (const float*)d_in[0];
    const float* codes = (const float*)d_in[1];
    const float* weight = (const float*)d_in[2];
    const float* A = (const float*)d_in[3];
    const float* Bm = (const float*)d_in[4];
    const float* bias = (const float*)d_in[5];
    const float* bctx = (const float*)d_in[6];
    float* out = (float*)d_out;
    float* ws = (float*)d_ws;

    dim3 block(256);
    dim3 grid1(OUT_F / 256, N_BATCH / BT, KC);   // (4, 8, 16) = 512 blocks
    gemm_partial<<<grid1, block, 0, stream>>>(input, weight, ws);

    dim3 grid2(OUT_F / 256, N_BATCH);            // (4, 128) = 512 blocks
    reduce_epilogue<<<grid2, block, 0, stream>>>(
        input, codes, A, Bm, bias, bctx, ws, out);
}

// Round 5
// 80.138 us; speedup vs baseline: 1.5083x; 1.0402x over previous
//
#include <hip/hip_runtime.h>

#define N_BATCH 128
#define IN_F 1024
#define OUT_F 1024
#define KC 32                 // split-K factor
#define CHUNK (IN_F / KC)     // 32
#define BT 8                  // batch rows per block
#define J4 (OUT_F / 4)        // 256 float4 columns

// ---------------- Kernel 1: split-K GEMM partials ----------------
// grid (16 b-tiles, KC); block 256. Thread t owns float4 of columns (4t..4t+3)
// x BT rows. Inner loop: 1 float4 weight load + float4 LDS input reads ->
// 128 FMAs per 8 LDS instrs (was 16 FMAs per 16 ds_read_b32 in R4).
__global__ __launch_bounds__(256) void gemm_partial(
    const float* __restrict__ input,    // [128,1024]
    const float* __restrict__ weight,   // [1024,1024]
    float* __restrict__ ws)             // [KC,128,1024] partials
{
    __shared__ float s_in[BT][CHUNK];   // 1 KB
    const int t = threadIdx.x;
    const int b0 = blockIdx.x * BT;
    const int k = blockIdx.y;
    const int i0 = k * CHUNK;

    // stage BT x CHUNK input slab (64 float4)
    if (t < BT * CHUNK / 4) {
        const int row = t >> 3;          // t / (CHUNK/4)
        const int x = t & 7;             // t % (CHUNK/4)
        ((float4*)&s_in[0][0])[t] =
            ((const float4*)input)[(size_t)(b0 + row) * (IN_F / 4) + i0 / 4 + x];
    }
    __syncthreads();

    const float4* wp = (const float4*)weight + (size_t)i0 * J4 + t;
    float4 acc[BT];
    #pragma unroll
    for (int r = 0; r < BT; ++r) acc[r] = make_float4(0.f, 0.f, 0.f, 0.f);

    #pragma unroll
    for (int g = 0; g < CHUNK / 4; ++g) {        // 8 groups of 4 i's
        float4 a[BT];
        #pragma unroll
        for (int r = 0; r < BT; ++r)             // ds_read_b128 broadcast
            a[r] = ((const float4*)&s_in[r][0])[g];
        #pragma unroll
        for (int q = 0; q < 4; ++q) {
            const float4 w = wp[(size_t)(4 * g + q) * J4];   // 16B coalesced
            #pragma unroll
            for (int r = 0; r < BT; ++r) {
                const float av = (q == 0) ? a[r].x : (q == 1) ? a[r].y
                               : (q == 2) ? a[r].z : a[r].w;
                acc[r].x = fmaf(av, w.x, acc[r].x);
                acc[r].y = fmaf(av, w.y, acc[r].y);
                acc[r].z = fmaf(av, w.z, acc[r].z);
                acc[r].w = fmaf(av, w.w, acc[r].w);
            }
        }
    }

    float4* o = (float4*)ws + ((size_t)k * N_BATCH + b0) * J4 + t;
    #pragma unroll
    for (int r = 0; r < BT; ++r)
        o[(size_t)r * J4] = acc[r];
}

// ---------------- Kernel 2: reduce + rank-2 epilogue ----------------
// grid (128); block 256. Thread t owns float4 of columns 4t..4t+3 for row b.
__global__ __launch_bounds__(256) void reduce_epilogue(
    const float* __restrict__ input,
    const float* __restrict__ codes,    // [128,2,2]
    const float* __restrict__ A,        // [1024,2]
    const float* __restrict__ Bm,       // [2,1024]
    const float* __restrict__ bias,     // [1024]
    const float* __restrict__ bctx,     // [2,1024]
    const float* __restrict__ ws,
    float* __restrict__ out)
{
    const int b = blockIdx.x;
    const int t = threadIdx.x;

    // ---- u[r] = dot(input[b], A[:,r]) : thread handles i = 4t..4t+3 ----
    const float4 x4 = ((const float4*)input)[(size_t)b * (IN_F / 4) + t];
    const float2 a0 = ((const float2*)A)[4 * t + 0];
    const float2 a1 = ((const float2*)A)[4 * t + 1];
    const float2 a2 = ((const float2*)A)[4 * t + 2];
    const float2 a3 = ((const float2*)A)[4 * t + 3];
    float p0 = x4.x * a0.x + x4.y * a1.x + x4.z * a2.x + x4.w * a3.x;
    float p1 = x4.x * a0.y + x4.y * a1.y + x4.z * a2.y + x4.w * a3.y;
    #pragma unroll
    for (int off = 32; off > 0; off >>= 1) {
        p0 += __shfl_down(p0, off);
        p1 += __shfl_down(p1, off);
    }
    __shared__ float s_part[4][2];
    __shared__ float s_v[4];            // v0, v1, c00, c11
    const int wave = t >> 6;
    if ((t & 63) == 0) { s_part[wave][0] = p0; s_part[wave][1] = p1; }
    __syncthreads();
    if (t == 0) {
        const float u0 = s_part[0][0] + s_part[1][0] + s_part[2][0] + s_part[3][0];
        const float u1 = s_part[0][1] + s_part[1][1] + s_part[2][1] + s_part[3][1];
        const float c00 = codes[b * 4 + 0], c01 = codes[b * 4 + 1];
        const float c10 = codes[b * 4 + 2], c11 = codes[b * 4 + 3];
        s_v[0] = fmaf(u0, c00, u1 * c10);   // v[b,0]
        s_v[1] = fmaf(u0, c01, u1 * c11);   // v[b,1]
        s_v[2] = c00;
        s_v[3] = c11;
    }
    __syncthreads();
    const float v0 = s_v[0], v1 = s_v[1], c00 = s_v[2], c11 = s_v[3];

    // ---- sum KC partials (32 independent float4 loads, all in flight) ----
    const float4* wsp = (const float4*)ws;
    float4 sum = make_float4(0.f, 0.f, 0.f, 0.f);
    #pragma unroll
    for (int k = 0; k < KC; ++k) {
        const float4 p = wsp[((size_t)k * N_BATCH + b) * J4 + t];
        sum.x += p.x; sum.y += p.y; sum.z += p.z; sum.w += p.w;
    }

    const float4 B0 = ((const float4*)Bm)[t];
    const float4 B1 = ((const float4*)Bm)[J4 + t];
    const float4 bi = ((const float4*)bias)[t];
    const float4 bc0 = ((const float4*)bctx)[t];
    const float4 bc1 = ((const float4*)bctx)[J4 + t];

    float4 r;
    r.x = sum.x + v0 * B0.x + v1 * B1.x + bi.x + c00 * bc0.x + c11 * bc1.x;
    r.y = sum.y + v0 * B0.y + v1 * B1.y + bi.y + c00 * bc0.y + c11 * bc1.y;
    r.z = sum.z + v0 * B0.z + v1 * B1.z + bi.z + c00 * bc0.z + c11 * bc1.z;
    r.w = sum.w + v0 * B0.w + v1 * B1.w + bi.w + c00 * bc0.w + c11 * bc1.w;
    ((float4*)out)[(size_t)b * J4 + t] = r;
}

extern "C" void kernel_launch(void* const* d_in, const int* in_sizes, int n_in,
                              void* d_out, int out_size, void* d_ws, size_t ws_size,
                              hipStream_t stream) {
    const float* input = (const float*)d_in[0];
    const float* codes = (const float*)d_in[1];
    const float* weight = (const float*)d_in[2];
    const float* A = (const float*)d_in[3];
    const float* Bm = (const float*)d_in[4];
    const float* bias = (const float*)d_in[5];
    const float* bctx = (const float*)d_in[6];
    float* out = (float*)d_out;
    float* ws = (float*)d_ws;   // needs KC*128*1024*4 = 16 MB (ws is 256 MB)

    dim3 block(256);
    dim3 grid1(N_BATCH / BT, KC);   // (16, 32) = 512 blocks
    gemm_partial<<<grid1, block, 0, stream>>>(input, weight, ws);

    reduce_epilogue<<<dim3(N_BATCH), block, 0, stream>>>(
        input, codes, A, Bm, bias, bctx, ws, out);
}

// Round 6
// 77.693 us; speedup vs baseline: 1.5558x; 1.0315x over previous
//
#include <hip/hip_runtime.h>

#define N_BATCH 128
#define IN_F 1024
#define OUT_F 1024
#define BT 8              // batch rows per block
#define JT 32             // output cols per block
#define SEG 32            // K segments per block (32 i each)
#define RSTRIDE 36        // floats per row within a segment (32 + pad)
#define SSTRIDE 292       // floats per segment (8*36+4): bank-quad skew of 4/seg

// Single-dispatch fused kernel. grid (32 j-tiles, 16 b-tiles) = 512 blocks.
// Thread (jg = t&7, ks = t>>3): 4 cols x 8 rows x 32 i -> 1024 FMA.
// K-segments reduced through LDS (buffer reused); u,v computed in-block.
__global__ __launch_bounds__(256) void geps_one(
    const float* __restrict__ input,    // [128,1024]
    const float* __restrict__ codes,    // [128,2,2]
    const float* __restrict__ weight,   // [1024,1024]
    const float* __restrict__ A,        // [1024,2]
    const float* __restrict__ Bm,       // [2,1024]
    const float* __restrict__ bias,     // [1024]
    const float* __restrict__ bctx,     // [2,1024]
    float* __restrict__ out)            // [128,1024]
{
    __shared__ __align__(16) float s[SEG * SSTRIDE];   // 37.4 KB, dual-use
    __shared__ float s_u[BT][2];
    __shared__ float s_v[BT][4];        // v0, v1, c00, c11

    const int t = threadIdx.x;
    const int j0 = blockIdx.x * JT;
    const int b0 = blockIdx.y * BT;

    // ---- stage 8 rows x 1024 floats into swizzled LDS ----
    #pragma unroll
    for (int it = 0; it < 8; ++it) {
        const int F = t + 256 * it;          // float4 index, 0..2047
        const int r = F >> 8;                // row 0..7
        const int i4 = F & 255;              // float4-within-row
        const int ks = i4 >> 3, g = i4 & 7;
        const float4 val = ((const float4*)input)[(size_t)(b0 + r) * (IN_F / 4) + i4];
        *(float4*)&s[ks * SSTRIDE + r * RSTRIDE + 4 * g] = val;
    }
    __syncthreads();

    // ---- u[row][r] = dot(in_row, A[:,r]) : 16 groups x 16 lanes ----
    {
        const int grp = t >> 4, l = t & 15;
        const int row = grp >> 1, rr = grp & 1;
        float p = 0.f;
        #pragma unroll 4
        for (int ii = 0; ii < 64; ++ii) {
            const int i = l + 16 * ii;
            const float x = s[(i >> 5) * SSTRIDE + row * RSTRIDE + (i & 31)];
            p = fmaf(x, A[2 * i + rr], p);
        }
        #pragma unroll
        for (int off = 8; off > 0; off >>= 1)
            p += __shfl_down(p, off, 16);
        if (l == 0) s_u[row][rr] = p;
    }
    __syncthreads();

    if (t < BT) {
        const int b = b0 + t;
        const float u0 = s_u[t][0], u1 = s_u[t][1];
        const float c00 = codes[b * 4 + 0], c01 = codes[b * 4 + 1];
        const float c10 = codes[b * 4 + 2], c11 = codes[b * 4 + 3];
        s_v[t][0] = fmaf(u0, c00, u1 * c10);   // v[b,0]
        s_v[t][1] = fmaf(u0, c01, u1 * c11);   // v[b,1]
        s_v[t][2] = c00;
        s_v[t][3] = c11;
    }
    // no sync needed here: s_v consumed only after the next two barriers

    // ---- main loop: this thread's K-segment ----
    const int jg = t & 7, ks = t >> 3;
    const int col4 = (j0 >> 2) + jg;
    const float4* W4 = (const float4*)weight;
    const float* segbase = &s[ks * SSTRIDE];

    float4 acc[BT];
    #pragma unroll
    for (int r = 0; r < BT; ++r) acc[r] = make_float4(0.f, 0.f, 0.f, 0.f);

    #pragma unroll
    for (int g = 0; g < 8; ++g) {
        float4 a[BT];
        #pragma unroll
        for (int r = 0; r < BT; ++r)         // ds_read_b128, broadcast x8, no conflict
            a[r] = *(const float4*)&segbase[r * RSTRIDE + 4 * g];
        #pragma unroll
        for (int q = 0; q < 4; ++q) {
            const float4 w = W4[(size_t)(ks * 32 + 4 * g + q) * (OUT_F / 4) + col4];
            #pragma unroll
            for (int r = 0; r < BT; ++r) {
                const float av = (q == 0) ? a[r].x : (q == 1) ? a[r].y
                               : (q == 2) ? a[r].z : a[r].w;
                acc[r].x = fmaf(av, w.x, acc[r].x);
                acc[r].y = fmaf(av, w.y, acc[r].y);
                acc[r].z = fmaf(av, w.z, acc[r].z);
                acc[r].w = fmaf(av, w.w, acc[r].w);
            }
        }
    }
    __syncthreads();                         // all s_in reads done; s_v visible

    // ---- write partials into reused LDS buffer ----
    #pragma unroll
    for (int r = 0; r < BT; ++r)
        *(float4*)&s[ks * SSTRIDE + r * RSTRIDE + 4 * jg] = acc[r];
    __syncthreads();

    // ---- reduce across 32 segments + epilogue ----
    {
        const int row = t >> 5, col = t & 31;
        float sum = 0.f;
        #pragma unroll
        for (int k = 0; k < SEG; ++k)
            sum += s[k * SSTRIDE + row * RSTRIDE + col];

        const int j = j0 + col;
        const int b = b0 + row;
        const float v0 = s_v[row][0], v1 = s_v[row][1];
        const float c00 = s_v[row][2], c11 = s_v[row][3];
        out[(size_t)b * OUT_F + j] = sum
            + v0 * Bm[j] + v1 * Bm[OUT_F + j]
            + bias[j]
            + c00 * bctx[j] + c11 * bctx[OUT_F + j];
    }
}

extern "C" void kernel_launch(void* const* d_in, const int* in_sizes, int n_in,
                              void* d_out, int out_size, void* d_ws, size_t ws_size,
                              hipStream_t stream) {
    const float* input = (const float*)d_in[0];
    const float* codes = (const float*)d_in[1];
    const float* weight = (const float*)d_in[2];
    const float* A = (const float*)d_in[3];
    const float* Bm = (const float*)d_in[4];
    const float* bias = (const float*)d_in[5];
    const float* bctx = (const float*)d_in[6];
    float* out = (float*)d_out;

    dim3 grid(OUT_F / JT, N_BATCH / BT);   // (32, 16) = 512 blocks, 2/CU
    dim3 block(256);
    geps_one<<<grid, block, 0, stream>>>(input, codes, weight, A, Bm, bias, bctx, out);
}